// Round 1
// 756.425 us; speedup vs baseline: 1.0259x; 1.0259x over previous
//
#include <hip/hip_runtime.h>
#include <hip/hip_bf16.h>
#include <math.h>

#define D_MODEL 1024
#define SEQ 2048
#define BATCH 8

typedef unsigned short u16;
typedef __attribute__((ext_vector_type(8))) short bf16x8;
typedef __attribute__((ext_vector_type(4))) float f32x4;

__device__ inline u16 f2bf(float f) {
  __hip_bfloat16 h = __float2bfloat16(f);
  return __builtin_bit_cast(u16, h);
}
__device__ inline float bf2f(u16 u) {
  return __builtin_bit_cast(float, (unsigned)u << 16);
}

// async 16B global->LDS copy; LDS dest is wave-uniform base + lane*16
__device__ __forceinline__ void async_cp16(const u16* g, u16* l) {
  __builtin_amdgcn_global_load_lds(
      (const __attribute__((address_space(1))) void*)g,
      (__attribute__((address_space(3))) void*)l, 16, 0, 0);
}

// ---------------- LayerNorm: fp32 in -> bf16 out ----------------
__global__ __launch_bounds__(256) void ln_kernel(
    const float* __restrict__ x, const float* __restrict__ w,
    const float* __restrict__ b, u16* __restrict__ out) {
  int row = blockIdx.x;
  int t = threadIdx.x;
  const float4* xr = (const float4*)(x + (size_t)row * D_MODEL);
  float4 v = xr[t];
  float s = v.x + v.y + v.z + v.w;
  float s2 = v.x * v.x + v.y * v.y + v.z * v.z + v.w * v.w;
  for (int o = 32; o > 0; o >>= 1) {
    s += __shfl_down(s, o);
    s2 += __shfl_down(s2, o);
  }
  __shared__ float red[10];
  int wave = t >> 6, lane = t & 63;
  if (lane == 0) { red[wave] = s; red[4 + wave] = s2; }
  __syncthreads();
  if (t == 0) {
    float S = red[0] + red[1] + red[2] + red[3];
    float S2 = red[4] + red[5] + red[6] + red[7];
    float mu = S * (1.f / D_MODEL);
    float var = S2 * (1.f / D_MODEL) - mu * mu;
    red[8] = mu;
    red[9] = rsqrtf(var + 1e-5f);
  }
  __syncthreads();
  float mu = red[8], rstd = red[9];
  float4 w4 = ((const float4*)w)[t];
  float4 b4 = ((const float4*)b)[t];
  ushort4 o4;
  o4.x = f2bf((v.x - mu) * rstd * w4.x + b4.x);
  o4.y = f2bf((v.y - mu) * rstd * w4.y + b4.y);
  o4.z = f2bf((v.z - mu) * rstd * w4.z + b4.z);
  o4.w = f2bf((v.w - mu) * rstd * w4.w + b4.w);
  ((ushort4*)(out + (size_t)row * D_MODEL))[t] = o4;
}

// ---- Softmax over a 2048-wide bf16 row, IN PLACE (fp32 math) ----
__global__ __launch_bounds__(256) void softmax_bf16_kernel(u16* __restrict__ p) {
  int row = blockIdx.x;
  int t = threadIdx.x;
  int4 q = ((const int4*)(p + (size_t)row * SEQ))[t];
  u16 us[8];
  __builtin_memcpy(us, &q, 16);
  float vals[8];
  for (int i = 0; i < 8; i++) vals[i] = bf2f(us[i]);
  float m = vals[0];
  for (int i = 1; i < 8; i++) m = fmaxf(m, vals[i]);
  for (int o = 32; o > 0; o >>= 1) m = fmaxf(m, __shfl_down(m, o));
  __shared__ float red[6];
  int wave = t >> 6, lane = t & 63;
  if (lane == 0) red[wave] = m;
  __syncthreads();
  if (t == 0) red[4] = fmaxf(fmaxf(red[0], red[1]), fmaxf(red[2], red[3]));
  __syncthreads();
  m = red[4];
  float s = 0.f;
  for (int i = 0; i < 8; i++) { vals[i] = __expf(vals[i] - m); s += vals[i]; }
  for (int o = 32; o > 0; o >>= 1) s += __shfl_down(s, o);
  if (lane == 0) red[wave] = s;
  __syncthreads();
  if (t == 0) red[5] = red[0] + red[1] + red[2] + red[3];
  __syncthreads();
  float inv = 1.f / red[5];
  union { u16 us[8]; int4 v4; } pk;
  for (int i = 0; i < 8; i++) pk.us[i] = f2bf(vals[i] * inv);
  ((int4*)(p + (size_t)row * SEQ))[t] = pk.v4;
}

// ---------------- Weight fp32 [K,N] -> bf16 transposed [N,K] ----------------
__global__ __launch_bounds__(256) void wconv_t(
    const float* __restrict__ W, u16* __restrict__ Wt, int K, int N) {
  int k0 = blockIdx.x * 64, n0 = blockIdx.y * 64;
  __shared__ u16 tile[64][65];
  int t = threadIdx.x;
  for (int p = 0; p < 16; p++) {
    int idx = p * 256 + t;
    int r = idx >> 6, c = idx & 63;
    tile[r][c] = f2bf(W[(size_t)(k0 + r) * N + n0 + c]);
  }
  __syncthreads();
  for (int p = 0; p < 16; p++) {
    int idx = p * 256 + t;
    int r = idx >> 6, c = idx & 63;
    Wt[(size_t)(n0 + r) * K + k0 + c] = tile[c][r];
  }
}

enum { EPI_QKV = 0, EPI_SCALE_BF16 = 1, EPI_RESID_F32 = 2,
       EPI_GELU_BF16 = 3, EPI_BIAS_F32 = 4 };

// ---- 128x128 GEMM (2-barrier structure) — kept for PV ----
template <int EPI>
__global__ __launch_bounds__(256, 4) void gemm_bt(
    const u16* __restrict__ A, const u16* __restrict__ Bt,
    void* __restrict__ Cv, const float* __restrict__ bias,
    const float* __restrict__ resid, u16* __restrict__ vTp,
    int M, int N, int K, int lda, int ldb, int ldc, float scale,
    long long saB, long long sbB, long long scB, long long srB) {
  __shared__ __align__(16) u16 lA[128 * 64];
  __shared__ __align__(16) u16 lB[128 * 64];
  int t = threadIdx.x;
  int zb = blockIdx.z;
  A += (size_t)zb * saB;
  Bt += (size_t)zb * sbB;

  int gx = gridDim.x;
  int flat = blockIdx.x + gx * blockIdx.y;
  int rem = flat % (4 * gx);
  int m0 = ((flat / (4 * gx)) * 4 + (rem & 3)) * 128;
  int n0 = (rem >> 2) * 128;

  int wv = t >> 6, lane = t & 63;

  int srow = t >> 3;
  int scg = (t & 7) ^ ((t >> 3) & 7);
  int scol = scg << 3;
  const u16* gA = A + (size_t)(m0 + srow) * lda + scol;
  const u16* gB = Bt + (size_t)(n0 + srow) * ldb + scol;
  u16* lAd = lA + t * 8;
  u16* lBd = lB + t * 8;

  int wm = (wv >> 1) * 64, wn = (wv & 1) * 64;
  int lr = lane & 15, lq = lane >> 4;
  int keyr = lr & 7;
  f32x4 acc[4][4] = {};

  for (int k0 = 0; k0 < K; k0 += 64) {
    #pragma unroll
    for (int r = 0; r < 4; r++) {
      async_cp16(gA + (size_t)(r * 32) * lda, lAd + r * 2048);
      async_cp16(gB + (size_t)(r * 32) * ldb, lBd + r * 2048);
    }
    gA += 64; gB += 64;
    __syncthreads();
    #pragma unroll
    for (int ks = 0; ks < 2; ks++) {
      bf16x8 af[4], bfr[4];
      #pragma unroll
      for (int i = 0; i < 4; i++)
        af[i] = *(const bf16x8*)(lA + (wm + i * 16 + lr) * 64 +
                                 (((lq + 4 * ks) ^ keyr) << 3));
      #pragma unroll
      for (int j = 0; j < 4; j++)
        bfr[j] = *(const bf16x8*)(lB + (wn + j * 16 + lr) * 64 +
                                  (((lq + 4 * ks) ^ keyr) << 3));
      #pragma unroll
      for (int i = 0; i < 4; i++)
        #pragma unroll
        for (int j = 0; j < 4; j++)
          acc[i][j] = __builtin_amdgcn_mfma_f32_16x16x32_bf16(
              af[i], bfr[j], acc[i][j], 0, 0, 0);
    }
    __syncthreads();
  }

  float* Cf = (float*)Cv + (size_t)zb * scB;
  u16* Ch = (u16*)Cv + (size_t)zb * scB;
  const float* rz = resid + (size_t)zb * srB;

  if constexpr (EPI == EPI_QKV) {
    if (n0 >= 2048) {
      for (int i = 0; i < 4; i++) {
        int row0 = m0 + wm + i * 16 + lq * 4;
        int batch = row0 >> 11, s0 = row0 & 2047;
        for (int j = 0; j < 4; j++) {
          int d = n0 - 2048 + wn + j * 16 + lr;
          float bcol = bias[n0 + wn + j * 16 + lr];
          ushort4 o4;
          o4.x = f2bf(acc[i][j][0] + bcol);
          o4.y = f2bf(acc[i][j][1] + bcol);
          o4.z = f2bf(acc[i][j][2] + bcol);
          o4.w = f2bf(acc[i][j][3] + bcol);
          *(ushort4*)(vTp + (((size_t)batch * 1024 + d) << 11) + s0) = o4;
        }
      }
      return;
    }
  }

  for (int i = 0; i < 4; i++) {
    for (int j = 0; j < 4; j++) {
      int col = n0 + wn + j * 16 + lr;
      float bcol = (EPI == EPI_QKV || EPI == EPI_GELU_BF16 ||
                    EPI == EPI_BIAS_F32) ? bias[col] : 0.f;
      for (int r = 0; r < 4; r++) {
        int row = m0 + wm + i * 16 + lq * 4 + r;
        float v = acc[i][j][r];
        size_t off = (size_t)row * ldc + col;
        if constexpr (EPI == EPI_QKV) {
          Ch[off] = f2bf(v + bcol);
        } else if constexpr (EPI == EPI_SCALE_BF16) {
          Ch[off] = f2bf(v * scale);
        } else if constexpr (EPI == EPI_RESID_F32) {
          Cf[off] = v + rz[off];
        } else if constexpr (EPI == EPI_GELU_BF16) {
          float xx = v + bcol;
          float u = xx * (0.7978845608f + 0.0356774081f * xx * xx);
          float e = __expf(2.f * u);
          float th = 1.f - 2.f * __builtin_amdgcn_rcpf(e + 1.f);
          Ch[off] = f2bf(0.5f * xx * (1.f + th));
        } else {
          Cf[off] = v + bcol;
        }
      }
    }
  }
}

// ================================================================
// 256x256 8-phase GEMM (T2+T3+T4+T5): BK=64, 2 K-tiles/iter,
// 8 waves (2M x 4N), 512 threads, 128 KiB LDS, counted vmcnt.
// LDS: 8 chunks of 16KiB: chunk(buf,AB,kHalf) = ((buf*2+AB)*2+ks)*8192 u16.
// Chunk content lane-linear (gload_lds); bank swizzle applied on the
// GLOBAL source: phys 16B group pg = lg ^ ((row>>1)&3)  (2-way = free).
// Read side: u16 off = row*32 + ((lq ^ ((lr>>1)&3))<<3).
// ================================================================
#define PHB() do { asm volatile("" ::: "memory");      \
    __builtin_amdgcn_sched_barrier(0);                 \
    __builtin_amdgcn_s_barrier();                      \
    __builtin_amdgcn_sched_barrier(0);                 \
    asm volatile("" ::: "memory"); } while (0)

#define LDA_(t_, ks_, fi_) \
  (*(const bf16x8*)(lds + (((t_) & 1) * 4 + (ks_)) * 8192 + aoff + (fi_) * 512))
#define LDB_(t_, ks_, fj_) \
  (*(const bf16x8*)(lds + (((t_) & 1) * 4 + 2 + (ks_)) * 8192 + boff + (fj_) * 512))

#define MMQ(base_) do {                                               \
    __builtin_amdgcn_s_setprio(1);                                    \
    _Pragma("unroll")                                                 \
    for (int ii = 0; ii < 4; ii++)                                    \
      _Pragma("unroll")                                               \
      for (int jj = 0; jj < 4; jj++)                                  \
        acc[(base_) + ii][jj] = __builtin_amdgcn_mfma_f32_16x16x32_bf16( \
            a_[ii], b_[jj], acc[(base_) + ii][jj], 0, 0, 0);          \
    __builtin_amdgcn_s_setprio(0); } while (0)

template <int EPI>
__global__ __launch_bounds__(512, 2) void gemm256(
    const u16* __restrict__ A, const u16* __restrict__ Bt,
    void* __restrict__ Cv, const float* __restrict__ bias,
    const float* __restrict__ resid, u16* __restrict__ vTp,
    int M, int N, int K, int lda, int ldb, int ldc, float scale,
    long long saB, long long sbB, long long scB, long long srB) {
  __shared__ __align__(16) u16 lds[65536];  // 128 KiB
  int t = threadIdx.x;
  int zb = blockIdx.z;
  A += (size_t)zb * saB;
  Bt += (size_t)zb * sbB;

  // XCD-bijective chunked swizzle (all our grids have nwg % 8 == 0)
  int gx = gridDim.x;
  int nwg = gx * gridDim.y;
  int flat = blockIdx.x + gx * blockIdx.y;
  int swz = flat;
  if (!(nwg & 7)) { int cpx = nwg >> 3; swz = (flat & 7) * cpx + (flat >> 3); }
  int mt = swz / gx, nt = swz % gx;
  int m0 = mt * 256, n0 = nt * 256;

  int wv = t >> 6, lane = t & 63, lr = lane & 15, lq = lane >> 4;
  int wm = (wv >> 2) * 128, wn = (wv & 3) * 64;
  int pg8 = (lq ^ ((lr >> 1) & 3)) << 3;  // swizzled 16B group (u16 units)
  int aoff = (wm + lr) * 32 + pg8;
  int boff = (wn + lr) * 32 + pg8;

  // staging: slot s = q*512 + t -> row s>>2, phys group s&3; fetch the
  // logical group lg = (s&3) ^ ((row>>1)&3) so the READ-side XOR undoes it.
  int r0 = t >> 2, r1 = r0 + 128;  // (r1>>1)&3 == (r0>>1)&3 (128 % 8 == 0)
  int c0 = ((t & 3) ^ ((r0 >> 1) & 3)) << 3;
  const u16* gA0 = A + (size_t)(m0 + r0) * lda + c0;
  const u16* gA1 = A + (size_t)(m0 + r1) * lda + c0;
  const u16* gB0 = Bt + (size_t)(n0 + r0) * ldb + c0;
  const u16* gB1 = Bt + (size_t)(n0 + r1) * ldb + c0;

  f32x4 acc[8][4] = {};
  int NT = K >> 6, NI = NT >> 1;

  auto stage = [&](int tile, int ab, int ks) {
    int ko = tile * 64 + ks * 32;
    u16* d = lds + ((tile & 1) * 4 + ab * 2 + ks) * 8192 + t * 8;
    if (ab) {
      async_cp16(gB0 + ko, d);
      async_cp16(gB1 + ko, d + 4096);
    } else {
      async_cp16(gA0 + ko, d);
      async_cp16(gA1 + ko, d + 4096);
    }
  };

  // prologue: 7-ahead pipeline minus one -> 6 half-tiles
  // order per tile: {A-K0, B-K0, A-K1, B-K1}
  stage(0, 0, 0); stage(0, 1, 0); stage(0, 0, 1); stage(0, 1, 1);
  stage(1, 0, 0); stage(1, 1, 0);
  asm volatile("s_waitcnt vmcnt(4)" ::: "memory");  // tile0 landed
  PHB();

  bf16x8 a_[4], b_[4];
  for (int it = 0; it < NI; it++) {
    int ta = 2 * it, tb = ta + 1, tc = ta + 2, td = ta + 3;
    bool ck = tc < NT, dk = td < NT;
    bool last = (it == NI - 1);

    // p0: (ta, ks0, Mlo)    stage tb.A-K1   (old data dead since prev p7)
    #pragma unroll
    for (int f = 0; f < 4; f++) a_[f] = LDA_(ta, 0, f);
    #pragma unroll
    for (int f = 0; f < 4; f++) b_[f] = LDB_(ta, 0, f);
    stage(tb, 0, 1);
    PHB();
    MMQ(0);
    PHB();

    // p1: (ta, ks0, Mhi)    stage tb.B-K1   (dead since prev p6)
    #pragma unroll
    for (int f = 0; f < 4; f++) a_[f] = LDA_(ta, 0, 4 + f);
    stage(tb, 1, 1);
    PHB();
    MMQ(4);
    PHB();

    // p2: (ta, ks1, Mlo)    stage tc.A-K0   (ta.A-K0 dead after p1)
    #pragma unroll
    for (int f = 0; f < 4; f++) a_[f] = LDA_(ta, 1, f);
    #pragma unroll
    for (int f = 0; f < 4; f++) b_[f] = LDB_(ta, 1, f);
    if (ck) stage(tc, 0, 0);
    PHB();
    MMQ(0);
    PHB();

    // p3: (ta, ks1, Mhi)    stage tc.B-K0   (ta.B-K0 dead after p0)
    #pragma unroll
    for (int f = 0; f < 4; f++) a_[f] = LDA_(ta, 1, 4 + f);
    if (ck) stage(tc, 1, 0);
    PHB();
    MMQ(4);
    if (last) { asm volatile("s_waitcnt vmcnt(0)" ::: "memory"); }
    else      { asm volatile("s_waitcnt vmcnt(4)" ::: "memory"); }  // tb landed
    PHB();

    // p4: (tb, ks0, Mlo)    stage tc.A-K1   (ta.A-K1 dead after p3)
    #pragma unroll
    for (int f = 0; f < 4; f++) a_[f] = LDA_(tb, 0, f);
    #pragma unroll
    for (int f = 0; f < 4; f++) b_[f] = LDB_(tb, 0, f);
    if (ck) stage(tc, 0, 1);
    PHB();
    MMQ(0);
    PHB();

    // p5: (tb, ks0, Mhi)    stage tc.B-K1   (ta.B-K1 dead after p2)
    #pragma unroll
    for (int f = 0; f < 4; f++) a_[f] = LDA_(tb, 0, 4 + f);
    if (ck) stage(tc, 1, 1);
    PHB();
    MMQ(4);
    PHB();

    // p6: (tb, ks1, Mlo)    stage td.A-K0   (tb.A-K0 dead after p5)
    #pragma unroll
    for (int f = 0; f < 4; f++) a_[f] = LDA_(tb, 1, f);
    #pragma unroll
    for (int f = 0; f < 4; f++) b_[f] = LDB_(tb, 1, f);
    if (dk) stage(td, 0, 0);
    PHB();
    MMQ(0);
    PHB();

    // p7: (tb, ks1, Mhi)    stage td.B-K0   (tb.B-K0 dead after p4)
    #pragma unroll
    for (int f = 0; f < 4; f++) a_[f] = LDA_(tb, 1, 4 + f);
    if (dk) stage(td, 1, 0);
    PHB();
    MMQ(4);
    asm volatile("s_waitcnt vmcnt(4)" ::: "memory");  // tc landed
    PHB();
  }

  float* Cf = (float*)Cv + (size_t)zb * scB;
  u16* Ch = (u16*)Cv + (size_t)zb * scB;
  const float* rz = resid + (size_t)zb * srB;

  if constexpr (EPI == EPI_QKV) {
    if (n0 >= 2048) {
      #pragma unroll
      for (int i = 0; i < 8; i++) {
        int row0 = m0 + wm + i * 16 + lq * 4;
        int batch = row0 >> 11, s0 = row0 & 2047;
        #pragma unroll
        for (int j = 0; j < 4; j++) {
          int d = n0 - 2048 + wn + j * 16 + lr;
          float bcol = bias[n0 + wn + j * 16 + lr];
          ushort4 o4;
          o4.x = f2bf(acc[i][j][0] + bcol);
          o4.y = f2bf(acc[i][j][1] + bcol);
          o4.z = f2bf(acc[i][j][2] + bcol);
          o4.w = f2bf(acc[i][j][3] + bcol);
          *(ushort4*)(vTp + (((size_t)batch * 1024 + d) << 11) + s0) = o4;
        }
      }
      return;
    }
  }

  for (int i = 0; i < 8; i++) {
    for (int j = 0; j < 4; j++) {
      int col = n0 + wn + j * 16 + lr;
      float bcol = (EPI == EPI_QKV || EPI == EPI_GELU_BF16 ||
                    EPI == EPI_BIAS_F32) ? bias[col] : 0.f;
      for (int r = 0; r < 4; r++) {
        int row = m0 + wm + i * 16 + lq * 4 + r;
        float v = acc[i][j][r];
        size_t off = (size_t)row * ldc + col;
        if constexpr (EPI == EPI_QKV) {
          Ch[off] = f2bf(v + bcol);
        } else if constexpr (EPI == EPI_SCALE_BF16) {
          Ch[off] = f2bf(v * scale);
        } else if constexpr (EPI == EPI_RESID_F32) {
          Cf[off] = v + rz[off];
        } else if constexpr (EPI == EPI_GELU_BF16) {
          float xx = v + bcol;
          float u = xx * (0.7978845608f + 0.0356774081f * xx * xx);
          float e = __expf(2.f * u);
          float th = 1.f - 2.f * __builtin_amdgcn_rcpf(e + 1.f);
          Ch[off] = f2bf(0.5f * xx * (1.f + th));
        } else {
          Cf[off] = v + bcol;
        }
      }
    }
  }
}

extern "C" void kernel_launch(void* const* d_in, const int* in_sizes, int n_in,
                              void* d_out, int out_size, void* d_ws, size_t ws_size,
                              hipStream_t stream) {
  const float* x      = (const float*)d_in[0];
  const float* ln1_w  = (const float*)d_in[1];
  const float* ln1_b  = (const float*)d_in[2];
  const float* W_attn = (const float*)d_in[3];
  const float* b_attn = (const float*)d_in[4];
  const float* ln2_w  = (const float*)d_in[5];
  const float* ln2_b  = (const float*)d_in[6];
  const float* W_fc   = (const float*)d_in[7];
  const float* b_fc   = (const float*)d_in[8];
  const float* W_proj = (const float*)d_in[9];
  const float* b_proj = (const float*)d_in[10];
  float* out = (float*)d_out;

  if (ws_size < 190840832ull) return;
  char* ws = (char*)d_ws;
  u16* hb   = (u16*)(ws + 0);
  u16* qk   = (u16*)(ws + 33554432ull);
  u16* vT   = (u16*)(ws + 100663296ull);
  u16* sc   = (u16*)(ws + 134217728ull);
  u16* fc   = (u16*)(ws + 33554432ull);
  u16* WaT  = (u16*)(ws + 167772160ull);
  u16* WfT  = (u16*)(ws + 174063616ull);
  u16* WpT  = (u16*)(ws + 182452224ull);

  wconv_t<<<dim3(1024 / 64, 3072 / 64), 256, 0, stream>>>(W_attn, WaT, 1024, 3072);
  wconv_t<<<dim3(1024 / 64, 4096 / 64), 256, 0, stream>>>(W_fc, WfT, 1024, 4096);
  wconv_t<<<dim3(4096 / 64, 1024 / 64), 256, 0, stream>>>(W_proj, WpT, 4096, 1024);

  ln_kernel<<<BATCH * SEQ, 256, 0, stream>>>(x, ln1_w, ln1_b, hb);

  // QKV: [16384,1024] @ [1024,3072] + b; q,k -> qk (ldc 2048), v -> vT transposed
  gemm256<EPI_QKV><<<dim3(12, 64, 1), 512, 0, stream>>>(
      hb, WaT, qk, b_attn, x, vT, BATCH * SEQ, 3072, 1024, 1024, 1024, 2048, 1.f,
      0, 0, 0, 0);

  // Attention in 2 chunks of 4 batches, batched over gridDim.z
  const float iss = 0.03125f;  // 1/sqrt(1024)
  for (int c = 0; c < 2; c++) {
    const u16* qb = qk + (size_t)c * 4 * SEQ * 2048;
    gemm256<EPI_SCALE_BF16><<<dim3(8, 8, 4), 512, 0, stream>>>(
        qb, qb + 1024, sc, nullptr, x, nullptr, SEQ, SEQ, 1024, 2048, 2048, SEQ,
        iss, (long long)SEQ * 2048, (long long)SEQ * 2048, (long long)SEQ * SEQ, 0);
    softmax_bf16_kernel<<<4 * SEQ, 256, 0, stream>>>(sc);
    gemm_bt<EPI_RESID_F32><<<dim3(8, 16, 4), 256, 0, stream>>>(
        sc, vT + (size_t)c * 4 * D_MODEL * SEQ,
        out + (size_t)c * 4 * SEQ * D_MODEL, nullptr,
        x + (size_t)c * 4 * SEQ * D_MODEL, nullptr, SEQ, D_MODEL, SEQ,
        SEQ, SEQ, D_MODEL, 1.f,
        (long long)SEQ * SEQ, (long long)D_MODEL * SEQ,
        (long long)SEQ * D_MODEL, (long long)SEQ * D_MODEL);
  }

  // LN2: out (fp32 residual) -> hb
  ln_kernel<<<BATCH * SEQ, 256, 0, stream>>>(out, ln2_w, ln2_b, hb);

  // FC + GELU: [16384,1024] @ [1024,4096] -> bf16
  gemm256<EPI_GELU_BF16><<<dim3(16, 64, 1), 512, 0, stream>>>(
      hb, WfT, fc, b_fc, x, nullptr, BATCH * SEQ, 4096, 1024, 1024, 1024, 4096,
      1.f, 0, 0, 0, 0);

  // Proj: [16384,4096] @ [4096,1024] + b -> fp32 out
  gemm256<EPI_BIAS_F32><<<dim3(4, 64, 1), 512, 0, stream>>>(
      fc, WpT, out, b_proj, x, nullptr, BATCH * SEQ, 1024, 4096, 4096, 4096,
      1024, 1.f, 0, 0, 0, 0);
}